// Round 9
// baseline (241.075 us; speedup 1.0000x reference)
//
#include <hip/hip_runtime.h>
#include <hip/hip_bf16.h>

// BertSelfAttention B=4,S=1024,HID=1024,H=16,D=64,MAXP=1024 — Round 9.
// R8 failed at absmax 3.27e-3: Toeplitz rolling buffer direction inverted —
// per-tile block must be the LOWER dist block [L-r0-64,+64) (prev iter holds
// the upper), I computed the upper. R9 = R8 with pre-loop Tcompute(L-r0s)
// and in-loop Tcompute(L-r0-64). Everything else unchanged: attn r-split
// waves (grid 64x16, 4 blk/CU), shuffle E^T, qkv global_load_lds staging.
// ws: Xs[0,8M) Wt[8M,14M) Db[14M,14.25M) Qf[15M) Kf[23M) Vt[31M)

#define EPSV 1e-8f

typedef short bfrag __attribute__((ext_vector_type(8)));   // 8 bf16
typedef float cfrag __attribute__((ext_vector_type(16)));  // C/D 32x32

__device__ __forceinline__ short f2bf(float f) {
    __hip_bfloat16 h = __float2bfloat16(f);
    return *reinterpret_cast<short*>(&h);
}
__device__ __forceinline__ float bf2f(short s) {
    unsigned int u = ((unsigned int)(unsigned short)s) << 16;
    return __builtin_bit_cast(float, u);
}
__device__ __forceinline__ unsigned int pk2(short a, short b) {
    return (unsigned int)(unsigned short)a | ((unsigned int)(unsigned short)b << 16);
}
__device__ __forceinline__ void gl2lds16(const void* g, void* l) {
    __builtin_amdgcn_global_load_lds(
        (const __attribute__((address_space(1))) unsigned int*)g,
        (__attribute__((address_space(3))) unsigned int*)l, 16, 0, 0);
}

// ---------------------------------------------------------------------------
// prep: fused cvt/swizzle (R7-verified).
__global__ __launch_bounds__(256) void prep(
    const float* __restrict__ hidden, const float* __restrict__ Wq,
    const float* __restrict__ Wk, const float* __restrict__ Wv,
    const float* __restrict__ dist,
    short* __restrict__ Xs, short* __restrict__ Wt, short* __restrict__ Db)
{
    __shared__ short Tl[32 * 72];
    const int bid = blockIdx.x, tid = threadIdx.x;

    if (bid < 2048) {                      // X: 128 m-tiles x 16 k-groups
        const int mt = bid >> 4, kg = bid & 15;
        const int m_l = tid >> 3, k8 = (tid & 7) * 8;
        const float* src = hidden + (size_t)(mt * 32 + m_l) * 1024 + kg * 64 + k8;
        float4 v0 = *(const float4*)src, v1 = *(const float4*)(src + 4);
        short o[8];
        o[0] = f2bf(v0.x); o[1] = f2bf(v0.y); o[2] = f2bf(v0.z); o[3] = f2bf(v0.w);
        o[4] = f2bf(v1.x); o[5] = f2bf(v1.y); o[6] = f2bf(v1.z); o[7] = f2bf(v1.w);
        *(bfrag*)&Tl[m_l * 72 + k8] = *(bfrag*)o;
        __syncthreads();
        const int l31 = tid & 31, q2 = (tid >> 5) & 1, kc = tid >> 6;
        bfrag r = *(const bfrag*)&Tl[l31 * 72 + kc * 16 + q2 * 8];
        *(bfrag*)(Xs + ((size_t)(mt * 64 + kg * 4 + kc) * 64 + q2 * 32 + l31) * 8) = r;
    } else if (bid < 3584) {               // W: 3 z x 32 n-tiles x 16 k-groups
        const int t = bid - 2048, z = t >> 9, nt = (t >> 4) & 31, kg = t & 15;
        const float* W = (z == 0) ? Wq : ((z == 1) ? Wk : Wv);
        const int k_l = tid >> 2, n8 = (tid & 3) * 8;
        const float* src = W + (size_t)(kg * 64 + k_l) * 1024 + nt * 32 + n8;
        float4 v0 = *(const float4*)src, v1 = *(const float4*)(src + 4);
        float vv[8] = {v0.x, v0.y, v0.z, v0.w, v1.x, v1.y, v1.z, v1.w};
#pragma unroll
        for (int i = 0; i < 8; i++)
            Tl[(n8 + i) * 72 + k_l] = f2bf(vv[i]);   // transpose into LDS
        __syncthreads();
        const int l31 = tid & 31, q2 = (tid >> 5) & 1, kc = tid >> 6;
        bfrag r = *(const bfrag*)&Tl[l31 * 72 + kc * 16 + q2 * 8];
        *(bfrag*)(Wt + (size_t)z * 1048576
                  + ((size_t)(nt * 64 + kg * 4 + kc) * 64 + q2 * 32 + l31) * 8) = r;
    } else {                               // dist: 2047*64 elems
        const int idx = (bid - 3584) * 256 + tid;
        if (idx < 16376) {
            const float* src = dist + (size_t)idx * 8;
            float4 v0 = *(const float4*)src, v1 = *(const float4*)(src + 4);
            short o[8];
            o[0] = f2bf(v0.x); o[1] = f2bf(v0.y); o[2] = f2bf(v0.z); o[3] = f2bf(v0.w);
            o[4] = f2bf(v1.x); o[5] = f2bf(v1.y); o[6] = f2bf(v1.z); o[7] = f2bf(v1.w);
            *(bfrag*)(Db + (size_t)idx * 8) = *(bfrag*)o;
        }
    }
}

// ---------------------------------------------------------------------------
// QKV GEMM: frag-major Xs/Wt staged to LDS via global_load_lds(16), BK=64,
// 128x128 block, 4 waves 2x2 of 64x64. Frag reads lane-linear (conflict-free).
__global__ __launch_bounds__(256) void qkv_mfma(
    const short* __restrict__ Xs, const short* __restrict__ Wt,
    const float* __restrict__ bq, const float* __restrict__ bk,
    const float* __restrict__ bv,
    short* __restrict__ Qf, short* __restrict__ Kf, short* __restrict__ Vt)
{
    __shared__ short As[8192];   // 4 m-tiles x 4 kc x 64 lanes x 8
    __shared__ short Bs[8192];

    const int z = blockIdx.z;
    const char* Xb = (const char*)Xs;
    const char* Wb = (const char*)(Wt + (size_t)z * 1048576);
    const float* bias = (z == 0) ? bq : ((z == 1) ? bk : bv);
    const float scale = (z == 0) ? 0.125f : 1.0f;   // fold 1/sqrt(D) into Q

    const int tid = threadIdx.x, lane = tid & 63, wid = tid >> 6;
    const int q2 = lane >> 5, l31 = lane & 31;
    const int wr = wid >> 1, wc = wid & 1;
    const int m0 = blockIdx.x * 128, n0 = blockIdx.y * 128;

    cfrag acc[2][2];
#pragma unroll
    for (int i = 0; i < 2; i++)
#pragma unroll
        for (int j = 0; j < 2; j++)
#pragma unroll
            for (int e = 0; e < 16; e++) acc[i][j][e] = 0.f;

    for (int kg = 0; kg < 16; kg++) {
        __syncthreads();   // prior frag reads complete
        const size_t abase = ((size_t)(((m0 >> 5) + wid) * 16 + kg)) * 4096;
        const size_t bbase = ((size_t)(((n0 >> 5) + wid) * 16 + kg)) * 4096;
#pragma unroll
        for (int i = 0; i < 4; i++) {
            gl2lds16(Xb + abase + i * 1024 + lane * 16,
                     (char*)As + wid * 4096 + i * 1024);
            gl2lds16(Wb + bbase + i * 1024 + lane * 16,
                     (char*)Bs + wid * 4096 + i * 1024);
        }
        __syncthreads();   // staged

        bfrag a[2][4], b[2][4];
#pragma unroll
        for (int i = 0; i < 2; i++)
#pragma unroll
            for (int kc = 0; kc < 4; kc++) {
                a[i][kc] = *(const bfrag*)&As[((2 * wr + i) * 4 + kc) * 512 + lane * 8];
                b[i][kc] = *(const bfrag*)&Bs[((2 * wc + i) * 4 + kc) * 512 + lane * 8];
            }
#pragma unroll
        for (int kc = 0; kc < 4; kc++)
#pragma unroll
            for (int mt = 0; mt < 2; mt++)
#pragma unroll
                for (int nt = 0; nt < 2; nt++)
                    acc[mt][nt] = __builtin_amdgcn_mfma_f32_32x32x16_bf16(
                        a[mt][kc], b[nt][kc], acc[mt][nt], 0, 0, 0);
    }

    // epilogue (R7-verified): scatter frag-major per bh
#pragma unroll
    for (int nt = 0; nt < 2; nt++) {
        const int c = n0 + wc * 64 + nt * 32 + l31;    // channel
        const float bval = bias[c];
        const int h = c >> 6;
        const int d = nt * 32 + l31;                   // c & 63
#pragma unroll
        for (int mt = 0; mt < 2; mt++) {
            const int tok0 = m0 + wr * 64 + mt * 32;
            const int bb = tok0 >> 10, s_base = tok0 & 1023;
            const size_t bhbase = (size_t)(bb * 16 + h) * 65536;
            if (z < 2) {
                short* outp = (z == 0) ? Qf : Kf;
                const size_t fbase = bhbase
                    + ((size_t)((s_base >> 5) * 4 + (d >> 4)) * 64
                       + ((d >> 3) & 1) * 32) * 8 + (d & 7);
#pragma unroll
                for (int reg = 0; reg < 16; reg++) {
                    const int row = (reg & 3) + 8 * (reg >> 2) + 4 * q2;
                    outp[fbase + (size_t)row * 8] = f2bf((acc[mt][nt][reg] + bval) * scale);
                }
            } else {
#pragma unroll
                for (int g = 0; g < 4; g++) {
                    const float e0 = acc[mt][nt][4 * g + 0] + bval;
                    const float e1 = acc[mt][nt][4 * g + 1] + bval;
                    const float e2 = acc[mt][nt][4 * g + 2] + bval;
                    const float e3 = acc[mt][nt][4 * g + 3] + bval;
                    uint2 w2;
                    w2.x = pk2(f2bf(e0), f2bf(e1));
                    w2.y = pk2(f2bf(e2), f2bf(e3));
                    const size_t flat = bhbase
                        + ((size_t)(nt * 64 + (s_base >> 4) + (g >> 1)) * 64
                           + (g & 1) * 32 + l31) * 8 + 4 * q2;
                    *(uint2*)(Vt + flat) = w2;
                }
            }
        }
    }
}

// ---------------------------------------------------------------------------
// Fused attention. grid (64 bh, 16 l-tiles of 64) = 1024 blocks (4/CU).
// 4 waves: w = (rw<<1)|lw. Wave owns 32 l-cols (l0+32lw) x r-half rw*512.
// Barrier-free main loop; E^T via register shuffle; epilogue combines halves.
__global__ __launch_bounds__(256) void attn_mfma(
    const short* __restrict__ Qf, const short* __restrict__ Kf,
    const short* __restrict__ Vt, const short* __restrict__ Db,
    const float* __restrict__ amask, const int* __restrict__ skim,
    float* __restrict__ out)
{
    __shared__ short Tb[128 * 132];   // rolling T[32w+l31][slot]; f32 scratch later
    __shared__ float Lg[1024];        // g[r] = exp(amask)*skim
    __shared__ float EsumL[2][64];

    const int tid = threadIdx.x, lane = tid & 63, w = tid >> 6;
    const int q2 = lane >> 5, l31 = lane & 31;
    const int lw = w & 1, rw = w >> 1;
    const int bh = blockIdx.x, b = bh >> 4, hh = bh & 15;
    const int l0 = blockIdx.y * 64;

    {
        const int r4 = tid * 4;
        float4 am = *(const float4*)(amask + b * 1024 + r4);
        int4 sk = *(const int4*)(skim + b * 1024 + r4);
        Lg[r4 + 0] = __expf(am.x) * (float)sk.x;
        Lg[r4 + 1] = __expf(am.y) * (float)sk.y;
        Lg[r4 + 2] = __expf(am.z) * (float)sk.z;
        Lg[r4 + 3] = __expf(am.w) * (float)sk.w;
    }
    __syncthreads();

    const short* Qg = Qf + (size_t)bh * 65536;
    const short* Kg = Kf + (size_t)bh * 65536;
    const short* Vg = Vt + (size_t)bh * 65536;

    bfrag qa[4];
#pragma unroll
    for (int c = 0; c < 4; c++)
        qa[c] = *(const bfrag*)(Qg + ((size_t)(((l0 >> 5) + lw) * 4 + c) * 64 + lane) * 8);

    cfrag oacc[2];
#pragma unroll
    for (int mt = 0; mt < 2; mt++)
#pragma unroll
        for (int e = 0; e < 16; e++) oacc[mt][e] = 0.f;
    float esum = 0.f;

    const int lrow = 32 * w + l31;        // wave-private Tb row
    const int L = l0 + 32 * lw;           // wave's l base
    const int lgl = L + l31;              // lane's l
    const int r0s = rw * 512;

    // Toeplitz block: T(l, dist) for dist in [bd, bd+64)
    auto Tcompute = [&](int bd) {
#pragma unroll
        for (int mt = 0; mt < 2; mt++) {
            cfrag t;
#pragma unroll
            for (int e = 0; e < 16; e++) t[e] = 0.f;
            const int drow = bd + 32 * mt + l31;
            const int er = min(max(drow + 1023, 0), 2046);
#pragma unroll
            for (int kc = 0; kc < 4; kc++) {
                bfrag pb = *(const bfrag*)(Db + (size_t)er * 64 + kc * 16 + q2 * 8);
                t = __builtin_amdgcn_mfma_f32_32x32x16_bf16(pb, qa[kc], t, 0, 0, 0);
            }
#pragma unroll
            for (int g = 0; g < 4; g++) {
                const int slot = (bd + 32 * mt + 8 * g + 4 * q2) & 127;
                uint2 w2;
                w2.x = pk2(f2bf(t[4 * g + 0]), f2bf(t[4 * g + 1]));
                w2.y = pk2(f2bf(t[4 * g + 2]), f2bf(t[4 * g + 3]));
                *(uint2*)&Tb[lrow * 132 + slot] = w2;
            }
        }
    };

    // ROLL DIRECTION FIX (R8 bug): pre-loop = UPPER block for first tile;
    // each tile computes its LOWER block [L-r0-64, +64). Buffer at tile r0
    // holds [L-r0-64, L-r0+63] >= needed [L-r0-63, L-r0+31].
    Tcompute(L - r0s);

    for (int rt = 0; rt < 8; rt++) {
        const int r0 = r0s + rt * 64;
        Tcompute(L - r0 - 64);

        // scores S^T = K . Q^T
        cfrag sfr[2];
#pragma unroll
        for (int mt = 0; mt < 2; mt++) {
#pragma unroll
            for (int e = 0; e < 16; e++) sfr[mt][e] = 0.f;
#pragma unroll
            for (int kc = 0; kc < 4; kc++) {
                bfrag kb = *(const bfrag*)(Kg
                    + ((size_t)(((r0 >> 5) + mt) * 4 + kc) * 64 + lane) * 8);
                sfr[mt] = __builtin_amdgcn_mfma_f32_32x32x16_bf16(
                    kb, qa[kc], sfr[mt], 0, 0, 0);
            }
        }

        // masked-softmax numerators -> packed P
        unsigned int P[2][8];
#pragma unroll
        for (int mt = 0; mt < 2; mt++) {
#pragma unroll
            for (int g = 0; g < 4; g++) {
                const int rb = r0 + 32 * mt + 8 * g + 4 * q2;
                float4 g4 = *(const float4*)&Lg[rb];
                short s4[4];
#pragma unroll
                for (int j = 0; j < 4; j++) {
                    const int dist = lgl - (rb + j);
                    const float tv = bf2f(Tb[lrow * 132 + (dist & 127)]);
                    const float gv = (j == 0) ? g4.x : (j == 1) ? g4.y
                                   : (j == 2) ? g4.z : g4.w;
                    const float e = __expf(sfr[mt][4 * g + j] + tv) * gv;
                    s4[j] = f2bf(e);
                    esum += bf2f(s4[j]);
                }
                P[mt][2 * g + 0] = pk2(s4[0], s4[1]);
                P[mt][2 * g + 1] = pk2(s4[2], s4[3]);
            }
        }

        // PV: O^T = V^T . E^T; E^T B-frags via shfl_xor(32) (R4==R5 verified)
#pragma unroll
        for (int kc = 0; kc < 4; kc++) {
            const int a = 4 * (kc & 1), mt = kc >> 1;
            const unsigned int x0 = __shfl_xor((int)P[mt][a + 0], 32);
            const unsigned int x1 = __shfl_xor((int)P[mt][a + 1], 32);
            const unsigned int x2 = __shfl_xor((int)P[mt][a + 2], 32);
            const unsigned int x3 = __shfl_xor((int)P[mt][a + 3], 32);
            union { unsigned int u[4]; bfrag f; } ef;
            ef.u[0] = q2 ? x2 : P[mt][a + 0];
            ef.u[1] = q2 ? x3 : P[mt][a + 1];
            ef.u[2] = q2 ? P[mt][a + 2] : x0;
            ef.u[3] = q2 ? P[mt][a + 3] : x1;
#pragma unroll
            for (int mtd = 0; mtd < 2; mtd++) {
                bfrag vb = *(const bfrag*)(Vg
                    + ((size_t)(mtd * 64 + (r0 >> 4) + kc) * 64 + lane) * 8);
                oacc[mtd] = __builtin_amdgcn_mfma_f32_32x32x16_bf16(
                    vb, ef.f, oacc[mtd], 0, 0, 0);
            }
        }
    }

    // ---- epilogue: combine rw halves ----
    const float es2 = esum + __shfl_xor(esum, 32);
    if (q2 == 0) EsumL[rw][32 * lw + l31] = es2;
    __syncthreads();                       // all Tb reads done; EsumL visible

    float* Osc = (float*)Tb;               // [64 d][68 l-pad]
    if (rw == 1) {
#pragma unroll
        for (int mtd = 0; mtd < 2; mtd++)
#pragma unroll
            for (int reg = 0; reg < 16; reg++) {
                const int d = 32 * mtd + (reg & 3) + 8 * (reg >> 2) + 4 * q2;
                Osc[d * 68 + 32 * lw + l31] = oacc[mtd][reg];
            }
    }
    __syncthreads();
    if (rw == 0) {
        const float den = EPSV + EsumL[0][32 * lw + l31] + EsumL[1][32 * lw + l31];
        const float inv = 1.0f / den;
        float* ob = out + ((size_t)(b * 1024 + lgl) * 1024) + hh * 64;
#pragma unroll
        for (int mtd = 0; mtd < 2; mtd++) {
#pragma unroll
            for (int g = 0; g < 4; g++) {
                const int db = 32 * mtd + 8 * g + 4 * q2;
                float4 o;
                o.x = (oacc[mtd][4 * g + 0] + Osc[(db + 0) * 68 + 32 * lw + l31]) * inv;
                o.y = (oacc[mtd][4 * g + 1] + Osc[(db + 1) * 68 + 32 * lw + l31]) * inv;
                o.z = (oacc[mtd][4 * g + 2] + Osc[(db + 2) * 68 + 32 * lw + l31]) * inv;
                o.w = (oacc[mtd][4 * g + 3] + Osc[(db + 3) * 68 + 32 * lw + l31]) * inv;
                *(float4*)(ob + db) = o;
            }
        }
    }
}

// ---------------------------------------------------------------------------
extern "C" void kernel_launch(void* const* d_in, const int* in_sizes, int n_in,
                              void* d_out, int out_size, void* d_ws, size_t ws_size,
                              hipStream_t stream) {
    const float* hidden = (const float*)d_in[0];
    const float* amask  = (const float*)d_in[1];
    const int*   skim   = (const int*)d_in[2];
    const float* Wq     = (const float*)d_in[3];
    const float* bq     = (const float*)d_in[4];
    const float* Wk     = (const float*)d_in[5];
    const float* bk     = (const float*)d_in[6];
    const float* Wv     = (const float*)d_in[7];
    const float* bv     = (const float*)d_in[8];
    const float* dist   = (const float*)d_in[9];
    float* out = (float*)d_out;

    char* w = (char*)d_ws;
    short* Xs  = (short*)(w);                        // 8 MB frag-major X
    short* Wt  = (short*)(w + ((size_t)8 << 20));    // 6 MB frag-major W^T
    short* Db  = (short*)(w + ((size_t)14 << 20));   // 0.25 MB dist bf16
    short* Qf  = (short*)(w + ((size_t)15 << 20));   // 8 MB frag-major Q
    short* Kf  = (short*)(w + ((size_t)23 << 20));   // 8 MB frag-major K
    short* Vt  = (short*)(w + ((size_t)31 << 20));   // 8 MB frag-major V^T

    prep<<<3648, 256, 0, stream>>>(hidden, Wq, Wk, Wv, dist, Xs, Wt, Db);
    qkv_mfma<<<dim3(32, 8, 3), 256, 0, stream>>>(Xs, Wt, bq, bk, bv, Qf, Kf, Vt);
    attn_mfma<<<dim3(64, 16), 256, 0, stream>>>(Qf, Kf, Vt, Db, amask, skim, out);
}